// Round 2
// baseline (378.172 us; speedup 1.0000x reference)
//
#include <hip/hip_runtime.h>

// CharAttention: per (b,w) causal char-attention; only row x_end_idx[b,w]
// survives the final gather -> compute only that row, with folded weights:
//   M_h = 0.25 * Wq_h @ Wk_h^T            -> rk_h[c] = xq . Mt_h[c][:]
//   P_h[e][c] = sum_d Wv[e][16h+d] Wproj[16h+d][c]
//                                          -> out[c] = sum_h y_h . Pt_h[c][:]
// Round-2 restructure: the kernel was DS-pipe-bound (~121 LDS ops/wave,
// VALUBusy 19%, HBM 5.6%). x is now read straight from global (per-problem
// working set ~3KB; 32 waves x 32 CUs x 3KB ~ 3MB/XCD fits L2), xq through a
// readfirstlane-scalarized pointer (SMEM path), and LDS holds only the three
// 256B cross-lane broadcast buffers (rks/ps/ys). Dynamic wave-uniform loops
// restore work proportional to L (avg 12.5 of 24 rows).
// DS ops/wave: ~121 -> ~35. Fences: 4 -> 3. LDS: 16KB -> 3KB/block.
//
// One wave per problem, 4 waves/block, grid 16384, 32 waves/CU.

#define CB      24
#define CC      32
#define DD      16
#define THREEC  96
#define NBW     (512 * 128)
#define WPB     4

__device__ __align__(16) float g_Mt[2][CC][CC];  // [h][c][e]
__device__ __align__(16) float g_Pt[2][CC][CC];  // [h][c][e]

__global__ void precompute_mp(const float* __restrict__ w_attn,
                              const float* __restrict__ w_proj)
{
    const int idx = blockIdx.x * 256 + threadIdx.x;   // 2048 entries
    const int h = idx >> 10, c = (idx >> 5) & 31, e = idx & 31;
    float m = 0.f, p = 0.f;
    #pragma unroll
    for (int d = 0; d < DD; ++d) {
        const int i = DD * h + d;
        m = fmaf(w_attn[e * THREEC + i],          w_attn[c * THREEC + CC + i], m);
        p = fmaf(w_attn[e * THREEC + 2 * CC + i], w_proj[i * CC + c],          p);
    }
    g_Mt[h][c][e] = 0.25f * m;                    // fold 1/sqrt(D)
    g_Pt[h][c][e] = p;
}

struct __align__(16) WaveSmem {
    float rks[2][CC];           // rk per head (256 B, 16B-aligned halves)
    float ps[2][CC];            // softmax probs; masked slots 0 (256 B)
    float ys[2][CC];            // p @ x per head (256 B)
};                              // 768 B -> 4 waves = 3 KB/block

__device__ __forceinline__ void wave_fence() {
    __asm__ volatile("s_waitcnt lgkmcnt(0)" ::: "memory");
}

__global__ __launch_bounds__(256, 8) void char_attn_kernel(
    const float* __restrict__ x,        // [B*W, 24, 32]
    const int*   __restrict__ xend,     // [B*W]
    float*       __restrict__ out)      // [B*W, 32]
{
    __shared__ WaveSmem sm[WPB];

    const int tid  = threadIdx.x;
    const int lane = tid & 63;
    const int wave = tid >> 6;
    WaveSmem& S = sm[wave];

    const int i32  = lane & 31;
    const int half = lane >> 5;

    // Scalarize the per-wave problem id and end index: all address math below
    // that uses only (sbid, sq) stays on the SGPR/SMEM path (zero DS, zero VGPR).
    const int sbid = __builtin_amdgcn_readfirstlane(blockIdx.x * WPB + wave);
    const int sq   = __builtin_amdgcn_readfirstlane(xend[sbid]);
    const int L    = sq + 1;

    const float* __restrict__ xb = x + (size_t)sbid * (CB * CC);
    const float* __restrict__ xq = xb + sq * CC;    // scalar address (s_load)

    // ---- rk: lane=(c=i32, h=half): rks[h][c] = xq . Mt[h][c][:] ----
    {
        const float4* m4 = (const float4*)&g_Mt[half][i32][0];
        float a0 = 0.f, a1 = 0.f, a2 = 0.f, a3 = 0.f;
        #pragma unroll
        for (int e4 = 0; e4 < 8; ++e4) {
            const float4 mv = m4[e4];                       // L1-hot, per-lane
            const float4 xv = *(const float4*)(xq + e4 * 4); // scalar, K$-hot
            a0 = fmaf(mv.x, xv.x, a0);
            a1 = fmaf(mv.y, xv.y, a1);
            a2 = fmaf(mv.z, xv.z, a2);
            a3 = fmaf(mv.w, xv.w, a3);
        }
        S.rks[half][i32] = (a0 + a1) + (a2 + a3);
    }
    wave_fence();                               // rks visible (in-wave)

    // ---- scores + softmax: lane=(h=half, j=i32) ----
    {
        float sc = -INFINITY;
        if (i32 <= sq) {
            const float4* xr  = (const float4*)(xb + i32 * CC);  // row j, global
            const float4* rk4 = (const float4*)&S.rks[half][0];  // b128 broadcast
            float a0 = 0.f, a1 = 0.f, a2 = 0.f, a3 = 0.f;
            #pragma unroll
            for (int e4 = 0; e4 < 8; ++e4) {
                const float4 rv = rk4[e4];
                const float4 xv = xr[e4];
                a0 = fmaf(rv.x, xv.x, a0);
                a1 = fmaf(rv.y, xv.y, a1);
                a2 = fmaf(rv.z, xv.z, a2);
                a3 = fmaf(rv.w, xv.w, a3);
            }
            sc = (a0 + a1) + (a2 + a3);
        }
        float m = sc;
        #pragma unroll
        for (int off = 16; off >= 1; off >>= 1)
            m = fmaxf(m, __shfl_xor(m, off));
        const float e = (i32 <= sq) ? __expf(sc - m) : 0.f;
        float sum = e;
        #pragma unroll
        for (int off = 16; off >= 1; off >>= 1)
            sum += __shfl_xor(sum, off);
        S.ps[half][i32] = __fdividef(e, sum);   // 0 for masked j
    }
    wave_fence();                               // ps visible

    // ---- y: lane=(c=i32, h=half): ys[h][c] = sum_j p[h][j] x[j][c] ----
    // Dynamic wave-uniform trip count (avg 12.5); x column reads are fully
    // coalesced (128 B/instr) and L2-hot from the scores phase.
    {
        float a0 = 0.f, a1 = 0.f;
        int j = 0;
        for (; j + 1 < L; j += 2) {
            const float2 p2 = *(const float2*)&S.ps[half][j];    // b64 broadcast
            a0 = fmaf(p2.x, xb[j * CC + i32],       a0);
            a1 = fmaf(p2.y, xb[(j + 1) * CC + i32], a1);
        }
        if (j < L)
            a0 = fmaf(S.ps[half][j], xb[j * CC + i32], a0);
        S.ys[half][i32] = a0 + a1;
    }
    wave_fence();                               // ys visible

    // ---- out[c] = sum_h ys[h] . Pt[h][c][:] + residual ----
    {
        const float4* p4 = (const float4*)&g_Pt[half][i32][0];
        const float4* y4 = (const float4*)&S.ys[half][0];        // b128 broadcast
        float a0 = 0.f, a1 = 0.f, a2 = 0.f, a3 = 0.f;
        #pragma unroll
        for (int e4 = 0; e4 < 8; ++e4) {
            const float4 pv = p4[e4];
            const float4 yv = y4[e4];
            a0 = fmaf(pv.x, yv.x, a0);
            a1 = fmaf(pv.y, yv.y, a1);
            a2 = fmaf(pv.z, yv.z, a2);
            a3 = fmaf(pv.w, yv.w, a3);
        }
        float t = (a0 + a1) + (a2 + a3);
        t += __shfl_xor(t, 32);                 // combine the two heads
        if (lane < CC)
            out[(size_t)sbid * CC + i32] = t + xq[i32];  // residual: coalesced, L2-hot
    }
}

extern "C" void kernel_launch(void* const* d_in, const int* in_sizes, int n_in,
                              void* d_out, int out_size, void* d_ws, size_t ws_size,
                              hipStream_t stream) {
    const float* x      = (const float*)d_in[0];
    const int*   xend   = (const int*)d_in[1];
    const float* w_attn = (const float*)d_in[2];
    const float* w_proj = (const float*)d_in[3];
    float* out = (float*)d_out;

    precompute_mp<<<dim3(8), dim3(256), 0, stream>>>(w_attn, w_proj);
    char_attn_kernel<<<dim3(NBW / WPB), dim3(WPB * 64), 0, stream>>>(
        x, xend, out);
}

// Round 3
// 294.567 us; speedup vs baseline: 1.2838x; 1.2838x over previous
//
#include <hip/hip_runtime.h>

// CharAttention: per (b,w) causal char-attention; only row x_end_idx[b,w]
// survives the final gather -> compute only that row, with folded weights:
//   Mt[h][c][e] = 0.25 * sum_d Wq[e][16h+d] Wk[c][16h+d]  -> rk_h[c] = xq . Mt[h][c][:]
//   Pt[h][c][e] = sum_d Wv[e][16h+d] Wproj[16h+d][c]      -> out[c] = sum_h y_h . Pt[h][c][:]
// Round-3: R1/R2 showed the kernel is bound by per-wave DS-pipe cycles plus
// critical-path latency, NOT VALU/HBM. This version minimizes DS ops (~69/wave
// vs R0's ~170) and keeps every VMEM access coalesced:
//  - x staged in LDS once (coalesced float2, dynamic wave-uniform trip count)
//  - M/P tables stored transposed [h][e4][c] as float4 -> coalesced, L1-hot
//  - xq read via SCALAR loads (readfirstlane'd pointer -> s_load, SMEM pipe):
//    rk phase has zero LDS reads, so stage+rk share ONE fence (3 fences total)
//  - rks/ys broadcast reads as b128, ps as b64 pairs
// One wave per problem, 4 waves/block, grid 16384, 15.75 KB LDS -> 32 waves/CU.

#define CB      24
#define CC      32
#define DD      16
#define THREEC  96
#define NBW     (512 * 128)
#define WPB     4
#define XSS     34              // xs row stride: even (float2-aligned), <=2-way banks

__device__ __align__(16) float4 g_M4[2][8][CC];  // [h][e4][c] = Mt[h][c][4e4..4e4+3]
__device__ __align__(16) float4 g_P4[2][8][CC];  // [h][e4][c] = Pt[h][c][4e4..4e4+3]

__global__ void precompute_mp(const float* __restrict__ w_attn,
                              const float* __restrict__ w_proj)
{
    const int idx = blockIdx.x * 256 + threadIdx.x;   // 512 entries
    const int h = idx >> 8, e4 = (idx >> 5) & 7, c = idx & 31;
    float m[4], p[4];
    #pragma unroll
    for (int k = 0; k < 4; ++k) {
        const int e = 4 * e4 + k;
        float mm = 0.f, pp = 0.f;
        #pragma unroll
        for (int d = 0; d < DD; ++d) {
            const int i = DD * h + d;
            mm = fmaf(w_attn[e * THREEC + i],          w_attn[c * THREEC + CC + i], mm);
            pp = fmaf(w_attn[e * THREEC + 2 * CC + i], w_proj[i * CC + c],          pp);
        }
        m[k] = 0.25f * mm;                        // fold 1/sqrt(D)
        p[k] = pp;
    }
    g_M4[h][e4][c] = make_float4(m[0], m[1], m[2], m[3]);
    g_P4[h][e4][c] = make_float4(p[0], p[1], p[2], p[3]);
}

struct __align__(16) WaveSmem {
    float xs[CB][XSS];          // staged x rows (3264 B, 16B-aligned)
    float rks[2][CC];           // rk per head (offset 3264, 16B-aligned halves)
    float ps[2][CC];            // softmax probs (offset 3520)
    float ys[2][CC];            // p @ x per head (offset 3776)
};                              // 4032 B -> 4 waves = 15.75 KB/block

__device__ __forceinline__ void wave_fence() {
    __asm__ volatile("s_waitcnt lgkmcnt(0)" ::: "memory");
}

__global__ __launch_bounds__(256, 8) void char_attn_kernel(
    const float* __restrict__ x,        // [B*W, 24, 32]
    const int*   __restrict__ xend,     // [B*W]
    float*       __restrict__ out)      // [B*W, 32]
{
    __shared__ WaveSmem sm[WPB];

    const int tid  = threadIdx.x;
    const int lane = tid & 63;
    const int wave = tid >> 6;
    WaveSmem& S = sm[wave];

    const int i32  = lane & 31;
    const int half = lane >> 5;

    // Wave-uniform scalars -> SGPR; all derived addresses stay scalar.
    const int sbid = __builtin_amdgcn_readfirstlane(blockIdx.x * WPB + wave);
    const int sq   = __builtin_amdgcn_readfirstlane(xend[sbid]);
    const int L    = sq + 1;

    const float* __restrict__ xb = x + (size_t)sbid * (CB * CC);
    const float* __restrict__ xq = xb + sq * CC;    // scalar address -> s_load

    // ---- stage x rows 0..sq into LDS (coalesced float2, dynamic trip) ----
    {
        const float2* xb2 = (const float2*)xb;
        const int n2 = L * (CC / 2);            // avg 200, max 384
        for (int t = lane; t < n2; t += 64) {
            float2 v = xb2[t];
            const int r = t >> 4, c = (t & 15) * 2;
            *(float2*)&S.xs[r][c] = v;          // 8B-aligned (XSS even)
        }
    }
    // NO fence here: rk phase touches no LDS reads; one fence covers both.

    // ---- rk: lane=(c=i32, h=half): rks[h][c] = xq . Mt[h][c][:] ----
    // Weights coalesced float4 (L1-hot); xq via scalar loads (SMEM pipe).
    {
        float a0 = 0.f, a1 = 0.f, a2 = 0.f, a3 = 0.f;
        #pragma unroll
        for (int e4 = 0; e4 < 8; ++e4) {
            const float4 mv = g_M4[half][e4][i32];           // coalesced VMEM
            const float4 xv = *(const float4*)(xq + e4 * 4); // s_load_dwordx4
            a0 = fmaf(mv.x, xv.x, a0);
            a1 = fmaf(mv.y, xv.y, a1);
            a2 = fmaf(mv.z, xv.z, a2);
            a3 = fmaf(mv.w, xv.w, a3);
        }
        S.rks[half][i32] = (a0 + a1) + (a2 + a3);
    }
    wave_fence();                               // xs-writes + rks-write visible

    // ---- scores + softmax: lane=(h=half, j=i32) ----
    {
        float sc = -INFINITY;
        if (i32 <= sq) {
            const float4* rk4 = (const float4*)&S.rks[half][0];  // b128 broadcast
            float a0 = 0.f, a1 = 0.f, a2 = 0.f, a3 = 0.f;
            #pragma unroll
            for (int e4 = 0; e4 < 8; ++e4) {
                const float4 rv = rk4[e4];
                const float2 x0 = *(const float2*)&S.xs[i32][e4 * 4];     // b64, 2-way
                const float2 x1 = *(const float2*)&S.xs[i32][e4 * 4 + 2];
                a0 = fmaf(rv.x, x0.x, a0);
                a1 = fmaf(rv.y, x0.y, a1);
                a2 = fmaf(rv.z, x1.x, a2);
                a3 = fmaf(rv.w, x1.y, a3);
            }
            sc = (a0 + a1) + (a2 + a3);
        }
        float m = sc;
        #pragma unroll
        for (int off = 16; off >= 1; off >>= 1)
            m = fmaxf(m, __shfl_xor(m, off));
        const float e = (i32 <= sq) ? __expf(sc - m) : 0.f;
        float sum = e;
        #pragma unroll
        for (int off = 16; off >= 1; off >>= 1)
            sum += __shfl_xor(sum, off);
        S.ps[half][i32] = __fdividef(e, sum);   // 0 for masked j
    }
    wave_fence();                               // ps visible

    // ---- y: lane=(c=i32, h=half): ys[h][c] = sum_j p[h][j] xs[j][c] ----
    // Dynamic wave-uniform trip count (avg 12.5 of 24).
    {
        float a0 = 0.f, a1 = 0.f;
        int j = 0;
        for (; j + 1 < L; j += 2) {
            const float2 p2 = *(const float2*)&S.ps[half][j];    // b64 broadcast
            a0 = fmaf(p2.x, S.xs[j][i32],     a0);               // b32 conflict-free
            a1 = fmaf(p2.y, S.xs[j + 1][i32], a1);
        }
        if (j < L)
            a0 = fmaf(S.ps[half][j], S.xs[j][i32], a0);
        S.ys[half][i32] = a0 + a1;
    }
    wave_fence();                               // ys visible

    // ---- out[c] = sum_h ys[h] . Pt[h][c][:] + residual ----
    {
        const float4* y4 = (const float4*)&S.ys[half][0];        // b128 broadcast
        float a0 = 0.f, a1 = 0.f, a2 = 0.f, a3 = 0.f;
        #pragma unroll
        for (int e4 = 0; e4 < 8; ++e4) {
            const float4 pv = g_P4[half][e4][i32];               // coalesced VMEM
            const float4 yv = y4[e4];
            a0 = fmaf(pv.x, yv.x, a0);
            a1 = fmaf(pv.y, yv.y, a1);
            a2 = fmaf(pv.z, yv.z, a2);
            a3 = fmaf(pv.w, yv.w, a3);
        }
        float t = (a0 + a1) + (a2 + a3);
        t += __shfl_xor(t, 32);                 // combine the two heads
        if (lane < CC)
            out[(size_t)sbid * CC + i32] = t + S.xs[sq][i32];    // residual from LDS
    }
}

extern "C" void kernel_launch(void* const* d_in, const int* in_sizes, int n_in,
                              void* d_out, int out_size, void* d_ws, size_t ws_size,
                              hipStream_t stream) {
    const float* x      = (const float*)d_in[0];
    const int*   xend   = (const int*)d_in[1];
    const float* w_attn = (const float*)d_in[2];
    const float* w_proj = (const float*)d_in[3];
    float* out = (float*)d_out;

    precompute_mp<<<dim3(2), dim3(256), 0, stream>>>(w_attn, w_proj);
    char_attn_kernel<<<dim3(NBW / WPB), dim3(WPB * 64), 0, stream>>>(
        x, xend, out);
}